// Round 6
// baseline (215.661 us; speedup 1.0000x reference)
//
#include <hip/hip_runtime.h>
#include <hip/hip_bf16.h>

// m=64 sample rows + 1 target row = 65 rows of Nk = 524288 f32 each.
// Score reduces to the 65x65 Gram matrix + O(m^2) scalar epilogue.
// time_points (d_in[2]) cancels in all pairwise differences -> unused.
//
// R6: BLOCKED k-ranges. R1-R5 all interleaved chunks across waves
// (c += nwaves), so each wave's per-row address hopped 256 KB between
// stages -> ~1M isolated 128-B DRAM touches at 2-MB row stride ->
// row-activation bound (~1.8 TB/s vs 6.9 TB/s the fills sustain).
// Now wave w owns the CONTIGUOUS chunk range [w*per, w*per+per): each
// row is read as a sequential 1-KB stream per wave (4 KB per block),
// DRAM pages are consumed whole. Everything else unchanged from R5:
// wave-private double-buffered LDS, 9x global_load_lds per chunk,
// counted vmcnt(9), swizzled read, atomic-free reduction.
#define NROW 65
#define GP   80            // padded gram dim (5 tiles of 16)
#define GE   (GP * GP)     // 6400 f32
#define CHF  32            // f32 per row per chunk (one MFMA K-step)
#define ROWB 128           // bytes per LDS row (CHF*4)
#define NRB  66            // rows per buffer: 65 real + 1 garbage (reads clamp)
#define BUFB (NRB * ROWB)  // 8448 B
#define WBUF (2 * BUFB)    // per-wave double buffer
#define TPB  256           // 4 waves
#define GRID_MAX 512

typedef float  f32x4  __attribute__((ext_vector_type(4)));
typedef __bf16 bf16x8 __attribute__((ext_vector_type(8)));

__device__ __forceinline__ void gl_lds16(const void* g, void* l) {
  __builtin_amdgcn_global_load_lds(
      (const __attribute__((address_space(1))) void*)g,
      (__attribute__((address_space(3))) void*)l, 16, 0, 0);
}

__global__ __launch_bounds__(TPB) void gram_k(
    const float* __restrict__ X,   // [64][Nk]
    const float* __restrict__ T,   // [Nk]
    float* __restrict__ S,         // [gridDim.x][GE] slice output
    int Nk, int nch)
{
  // 4 waves x 16896 B = 67584 B; tail reduction reuses the first 25600 B.
  __shared__ __align__(16) char smem[4 * WBUF];
  const int tid  = threadIdx.x;
  const int wv   = tid >> 6;
  const int lane = tid & 63;
  const int lr   = lane & 15, kg = lane >> 4;
  const size_t Nkb = (size_t)Nk * 4;

  char* myb = smem + wv * WBUF;

  f32x4 acc[15];
#pragma unroll
  for (int i = 0; i < 15; ++i) acc[i] = (f32x4){0.f, 0.f, 0.f, 0.f};

  // Stage chunk c into this wave's buffer: 8 instrs x 8 rows x 128 B + 1
  // partial instr for row 64 (target). LDS dest is linear (gload_lds writes
  // base + lane*16); source is pre-swizzled so physical 16B-slot p of row r
  // holds global slot p^(r&7)  (rule 21: linear dest + inv-swz src + swz read).
  auto stage = [&](char* buf, int c) {
    const size_t colb = (size_t)c * ROWB;
#pragma unroll
    for (int i = 0; i < 8; ++i) {
      const int r  = 8 * i + (lane >> 3);
      const int ss = (lane & 7) ^ ((lane >> 3) & 7);   // (l&7)^(r&7)
      const char* src = (const char*)X + (size_t)r * Nkb + colb + ss * 16;
      gl_lds16(src, buf + i * 1024);
    }
    if (lane < 8) {                    // row 64; (64&7)=0 -> no swizzle
      const char* src = (const char*)T + colb + lane * 16;
      gl_lds16(src, buf + 64 * ROWB);
    }
  };

  // Blocked contiguous chunk range for this wave.
  const int nwaves = gridDim.x * (TPB / 64);
  const int gw  = blockIdx.x * (TPB / 64) + wv;
  const int per = nch / nwaves;
  const int rem = nch % nwaves;
  const int cnt = per + (gw < rem ? 1 : 0);
  int c = gw * per + (gw < rem ? gw : rem);

  if (cnt > 0) {
    stage(myb, c);
    for (int it = 0; it < cnt; ++it) {
      char* cur = myb + (it & 1) * BUFB;
      char* nxt = myb + ((it & 1) ^ 1) * BUFB;
      const bool hn = (it + 1) < cnt;
      // Previous iteration's ds_reads consumed; then issue next-chunk loads
      // (SEQUENTIAL continuation of each row's stream) to fly during compute.
      asm volatile("s_waitcnt lgkmcnt(0)" ::: "memory");
      __builtin_amdgcn_sched_barrier(0);
      if (hn) stage(nxt, c + 1);
      if (hn) asm volatile("s_waitcnt vmcnt(9)" ::: "memory");  // cur complete
      else    asm volatile("s_waitcnt vmcnt(0)" ::: "memory");
      __builtin_amdgcn_sched_barrier(0);

      // Fragments: tile t, lane holds 8 f32 of row t*16+lr at float-offset
      // kg*8 within the 32-f32 chunk. Rows >65 clamp to garbage row 65 ->
      // pollutes only G entries with i or j >= 65 (each MFMA output element
      // (i,j) touches only A-row i / B-row j), which epilogue discards.
      bf16x8 f[5];
#pragma unroll
      for (int t = 0; t < 5; ++t) {
        int r = t * 16 + lr; if (r > 65) r = 65;
        const char* rb = cur + r * ROWB;
        const int sw = (r & 7) << 4;
        f32x4 a = *(const f32x4*)(rb + ((kg * 32) ^ sw));
        f32x4 b = *(const f32x4*)(rb + ((kg * 32 + 16) ^ sw));
        f[t] = (bf16x8){(__bf16)a.x, (__bf16)a.y, (__bf16)a.z, (__bf16)a.w,
                        (__bf16)b.x, (__bf16)b.y, (__bf16)b.z, (__bf16)b.w};
      }
#pragma unroll
      for (int I = 0; I < 5; ++I)
#pragma unroll
        for (int J = I; J < 5; ++J) {
          const int idx = I * 5 + J - (I * (I + 1)) / 2;
          acc[idx] = __builtin_amdgcn_mfma_f32_16x16x32_bf16(f[I], f[J], acc[idx], 0, 0, 0);
        }
      ++c;
    }
  }

  // Atomic-free block reduction: serialized wave rounds into LDS [80][80]
  // (reuses staging memory), then coalesced store of this block's slice.
  float* gl = (float*)smem;
  __syncthreads();
  for (int e = tid; e < GE; e += TPB) gl[e] = 0.f;
  __syncthreads();
  for (int w = 0; w < 4; ++w) {
    if (wv == w) {
#pragma unroll
      for (int I = 0; I < 5; ++I)
#pragma unroll
        for (int J = I; J < 5; ++J) {
          const int idx = I * 5 + J - (I * (I + 1)) / 2;
#pragma unroll
          for (int r = 0; r < 4; ++r) {
            const int grow = I * 16 + kg * 4 + r;   // C/D: row=(lane>>4)*4+reg
            const int gcol = J * 16 + lr;           //      col=lane&15
            gl[grow * GP + gcol] += acc[idx][r];
          }
        }
    }
    __syncthreads();
  }
  float* dst = S + (size_t)blockIdx.x * GE;
  for (int e = tid; e < GE; e += TPB) dst[e] = gl[e];
}

// R4 parallel slice reduction (measured fix: 121.7 us -> ~8 us).
#define RBLK 64
__global__ __launch_bounds__(256) void reduce_k(
    const float* __restrict__ S, float* __restrict__ G, int nsl)
{
  __shared__ float ps[4][RBLK];
  const int tid = threadIdx.x;
  const int e0  = blockIdx.x * RBLK;
  const int el  = tid & (RBLK - 1);
  const int p   = tid >> 6;            // 0..3
  const float* base = S + (size_t)p * GE + (e0 + el);
  float s = 0.f;
  int i = p;
#pragma unroll 8
  for (; i + 32 <= nsl; i += 32) {
    s += base[0];
    s += base[(size_t)4  * GE];
    s += base[(size_t)8  * GE];
    s += base[(size_t)12 * GE];
    s += base[(size_t)16 * GE];
    s += base[(size_t)20 * GE];
    s += base[(size_t)24 * GE];
    s += base[(size_t)28 * GE];
    base += (size_t)32 * GE;
  }
  for (; i < nsl; i += 4) { s += base[0]; base += (size_t)4 * GE; }
  ps[p][el] = s;
  __syncthreads();
  if (tid < RBLK)
    G[e0 + tid] = ps[0][tid] + ps[1][tid] + ps[2][tid] + ps[3][tid];
}

__global__ __launch_bounds__(256) void epilogue_k(
    const float* __restrict__ G, float* __restrict__ out)
{
  __shared__ float gl[GE];
  __shared__ float rx[4], rt[4];
  const int tid = threadIdx.x;
  for (int e = tid; e < GE; e += 256) gl[e] = G[e];
  __syncthreads();

  float accX = 0.f, accT = 0.f;
  for (int e = tid; e < GE; e += 256) {
    int i = e / GP, j = e % GP;
    if (j >= NROW || i >= j) continue;           // upper triangle, i<j
    float g  = gl[e];
    float d2 = gl[i * GP + i] + gl[j * GP + j] - 2.f * g;
    if (j < 64) accX += expf(-fmaxf(d2, 0.f));   // pair term (ref clamps d2)
    else        accT += expf(-d2);               // target term (no clamp)
  }
#pragma unroll
  for (int off = 32; off > 0; off >>= 1) {
    accX += __shfl_down(accX, off);
    accT += __shfl_down(accT, off);
  }
  const int wv = tid >> 6, lane = tid & 63;
  if (lane == 0) { rx[wv] = accX; rt[wv] = accT; }
  __syncthreads();
  if (tid == 0) {
    float sx = rx[0] + rx[1] + rx[2] + rx[3];
    float st = rt[0] + rt[1] + rt[2] + rt[3];
    // cross = (LAMBDA/2) * 2*sx / (m(m-1)) = sx/8064
    float score = sx / 8064.f - st / 64.f;
    score = fminf(fmaxf(score, -10.f), 10.f);
    out[0] = score;
  }
}

extern "C" void kernel_launch(void* const* d_in, const int* in_sizes, int n_in,
                              void* d_out, int out_size, void* d_ws, size_t ws_size,
                              hipStream_t stream) {
  const float* X = (const float*)d_in[0];   // generated_samples [64,4096,128]
  const float* T = (const float*)d_in[1];   // target_sample [4096,128]
  float* out = (float*)d_out;

  const int Nk  = in_sizes[1];              // 524288
  const int nch = Nk / CHF;                 // 16384 chunks of 32 f32

  // ws layout: [nsl][GE] slices | [GE] final G
  int nsl = (int)(ws_size / (GE * sizeof(float))) - 1;
  if (nsl > GRID_MAX) nsl = GRID_MAX;
  if (nsl < 1) nsl = 1;
  float* S = (float*)d_ws;
  float* G = S + (size_t)nsl * GE;

  gram_k<<<nsl, TPB, 0, stream>>>(X, T, S, Nk, nch);
  reduce_k<<<(GE / RBLK), 256, 0, stream>>>(S, G, nsl);
  epilogue_k<<<1, 256, 0, stream>>>(G, out);
}